// Round 1
// baseline (79.425 us; speedup 1.0000x reference)
//
#include <hip/hip_runtime.h>
#include <math.h>

#define GL_ORDER 10
#define TAB_N 512                // intervals over [0, BMAX]; node table = 513 floats in LDS
#define BMAX 1.3f
#define BLOCK 256
#define CHUNKS 4                 // float4 chunks per thread (was 2) -> grid halves, build redundancy halves
#define ELEMS_PER_BLOCK (BLOCK * 4 * CHUNKS)   // 4096

// Fast acos: Abramowitz-Stegun 4.4.45, |err| <= 5e-5 rad over [-1,1].
__device__ __forceinline__ float acos_fast(float x) {
    const float ax = fabsf(x);
    const float s  = __builtin_amdgcn_sqrtf(1.0f - ax);
    const float p  = fmaf(ax, fmaf(ax, fmaf(ax, -0.0187293f, 0.0742610f),
                                   -0.2121144f), 1.5707288f);
    const float r = s * p;
    return (x < 0.0f) ? (3.14159265358979323846f - r) : r;
}

// Full quadrature evaluation of lc(|b|) (no z mask).
__device__ float lc_eval(float bb, float r, float u0, float u1,
                         float c_core, float c_ann) {
    const float tj[GL_ORDER] = {
        0.013046735741414128f, 0.067468316655507744f, 0.160295215850487787f,
        0.283302302935376393f, 0.425562830509184362f, 0.574437169490815638f,
        0.716697697064623607f, 0.839704784149512213f, 0.932531683344492256f,
        0.986953264258585872f};
    const float wj[GL_ORDER] = {
        0.066671344308688138f, 0.149451349150580593f, 0.219086362515982044f,
        0.269266719309996355f, 0.295524224714752870f, 0.295524224714752870f,
        0.269266719309996355f, 0.219086362515982044f, 0.149451349150580593f,
        0.066671344308688138f};

    const float core_hi = fminf(fmaxf(r - bb, 0.0f), 1.0f);
    const float lo    = fminf(fabsf(bb - r), 1.0f);
    const float hi    = fminf(bb + r, 1.0f);
    const float width = fmaxf(hi - lo, 0.0f);

    const float b2r2 = fmaf(bb, bb, -r * r);
    const float twob = 2.0f * bb;

    float s_core = 0.0f;
    float s_ann  = 0.0f;

#pragma unroll
    for (int j = 0; j < GL_ORDER; ++j) {
        const float t = tj[j];

        const float rc   = core_hi * t;
        const float muc  = __builtin_amdgcn_sqrtf(fmaxf(fmaf(-rc, rc, 1.0f), 1e-12f));
        const float ommc = 1.0f - muc;
        const float Ic   = fmaf(-ommc, fmaf(u1, ommc, u0), 1.0f);
        s_core = fmaf(wj[j] * t, Ic, s_core);

        const float ra   = fmaf(width, t, lo);
        const float ra2  = ra * ra;
        const float mua  = __builtin_amdgcn_sqrtf(fmaxf(1.0f - ra2, 1e-12f));
        const float omma = 1.0f - mua;
        const float Ia   = fmaf(-omma, fmaf(u1, omma, u0), 1.0f);

        const float cosarg_raw = (b2r2 + ra2) * __builtin_amdgcn_rcpf(twob * ra);
        const float cosarg = fminf(fmaxf(cosarg_raw, -0.999999f), 0.999999f);
        const float ac = acos_fast(cosarg);

        s_ann = fmaf(wj[j] * Ia, ac * ra, s_ann);
    }

    return fmaf(c_core * core_hi * core_hi, s_core, c_ann * width * s_ann);
}

// Single fused kernel. Changes vs prior best:
//  1. PREFETCH: all global b/z loads are issued FIRST (into registers), so the
//     HBM stream overlaps the LDS table build instead of serializing after it.
//  2. CHUNKS 2->4: grid 1024->512 blocks; halves chip-wide redundant table
//     builds (2 blocks/CU -> build VALU wall ~1.4us, hidden under ~4.3us stream).
//  3. Early-out for table nodes with bb >= 1+r (lc is exactly 0 there).
__global__ __launch_bounds__(BLOCK) void LimbDarkLightCurve_55370718380097_kernel(
    const float* __restrict__ u, const float* __restrict__ bptr,
    const float* __restrict__ rptr, const float* __restrict__ zptr,
    float* __restrict__ out, int K) {
    __shared__ float fnode[TAB_N + 1];

    const float u0 = u[0];
    const float u1 = u[1];
    const float r  = rptr[0];
    const float inv_norm =
        1.0f / (3.14159265358979323846f *
                (1.0f - u0 * (1.0f / 3.0f) - u1 * (1.0f / 6.0f)));
    const float c_core = -3.14159265358979323846f * inv_norm;
    const float c_ann  = -inv_norm;

    const int base = blockIdx.x * ELEMS_PER_BLOCK;
    const bool full = (base + ELEMS_PER_BLOCK) <= K;   // block-uniform

    // ---- prefetch phase: issue all global loads before the table build ----
    float4 b4[CHUNKS], z4[CHUNKS];
    if (full) {
#pragma unroll
        for (int c = 0; c < CHUNKS; ++c) {
            const int i4 = base + (threadIdx.x + c * BLOCK) * 4;
            b4[c] = *reinterpret_cast<const float4*>(bptr + i4);
            z4[c] = *reinterpret_cast<const float4*>(zptr + i4);
        }
    }

    // ---- build phase: 513 nodes, 2 per thread (+1 extra on thread 0) ----
    const float hstep = BMAX / (float)TAB_N;
    const float blim  = 1.0f + r;   // lc(bb) == 0 exactly for bb >= 1+r
    for (int node = threadIdx.x; node <= TAB_N; node += BLOCK) {
        const float bb = (float)node * hstep;
        fnode[node] = (bb < blim)
                          ? lc_eval(bb, r, u0, u1, c_core, c_ann)
                          : 0.0f;
    }
    __syncthreads();

    // ---- lookup phase ----
    const float scale = (float)TAB_N / BMAX;

    if (full) {
#pragma unroll
        for (int c = 0; c < CHUNKS; ++c) {
            const int i4 = base + (threadIdx.x + c * BLOCK) * 4;
            float bs[4] = {b4[c].x, b4[c].y, b4[c].z, b4[c].w};
            float zs[4] = {z4[c].x, z4[c].y, z4[c].z, z4[c].w};
            float os[4];
#pragma unroll
            for (int k = 0; k < 4; ++k) {
                const float x = fabsf(bs[k]) * scale;
                int   i = (int)x;
                i = (i < TAB_N - 1) ? i : (TAB_N - 1);
                const float f  = x - (float)i;
                const float v0 = fnode[i];
                const float v1 = fnode[i + 1];
                const float v  = fmaf(f, v1 - v0, v0);
                os[k] = (zs[k] > 0.0f) ? v : 0.0f;
            }
            float4 o = {os[0], os[1], os[2], os[3]};
            *reinterpret_cast<float4*>(out + i4) = o;
        }
    } else {
        // tail block: scalar path, per chunk, clamped to K
        for (int c = 0; c < CHUNKS; ++c) {
            const int i4 = base + (threadIdx.x + c * BLOCK) * 4;
            const int iend = (i4 + 4 < K) ? (i4 + 4) : K;
            for (int i = i4; i < iend; ++i) {
                const float x = fabsf(bptr[i]) * scale;
                int   ii = (int)x;
                ii = (ii < TAB_N - 1) ? ii : (TAB_N - 1);
                const float f  = x - (float)ii;
                const float v0 = fnode[ii];
                const float v1 = fnode[ii + 1];
                const float v  = fmaf(f, v1 - v0, v0);
                out[i] = (zptr[i] > 0.0f) ? v : 0.0f;
            }
        }
    }
}

extern "C" void kernel_launch(void* const* d_in, const int* in_sizes, int n_in,
                              void* d_out, int out_size, void* d_ws, size_t ws_size,
                              hipStream_t stream) {
    const float* u = (const float*)d_in[0];
    const float* b = (const float*)d_in[1];
    const float* r = (const float*)d_in[2];
    const float* z = (const float*)d_in[3];
    float* out = (float*)d_out;
    const int K = in_sizes[1];

    const int grid = (K + ELEMS_PER_BLOCK - 1) / ELEMS_PER_BLOCK;
    LimbDarkLightCurve_55370718380097_kernel<<<grid, BLOCK, 0, stream>>>(
        u, b, r, z, out, K);
}